// Round 3
// baseline (731.685 us; speedup 1.0000x reference)
//
#include <hip/hip_runtime.h>
#include <stdint.h>

typedef __bf16 bf16x8 __attribute__((ext_vector_type(8)));
typedef float  f32x4  __attribute__((ext_vector_type(4)));

#define KCHUNKS 33              // K' = 66 rows (64 hid + bias + zero) x 16 n / 32
#define WPB     12              // waves per block
#define BLOCK   (WPB * 64)

// truncating f32->bf16 pack of two floats into one dword (x low, y high)
__device__ __forceinline__ uint32_t pack_trunc(float x, float y) {
    return __builtin_amdgcn_perm(__builtin_bit_cast(uint32_t, x),
                                 __builtin_bit_cast(uint32_t, y),
                                 0x03020706u);
}

__device__ __forceinline__ uint16_t f32_to_bf16_rne(float f) {
    uint32_t u = __builtin_bit_cast(uint32_t, f);
    u += 0x7FFFu + ((u >> 16) & 1u);
    return (uint16_t)(u >> 16);
}

__device__ __forceinline__ bf16x8 u4_as_bf16x8(uint32_t a, uint32_t b,
                                               uint32_t c, uint32_t d) {
    union { uint32_t u[4]; bf16x8 v; } x;
    x.u[0] = a; x.u[1] = b; x.u[2] = c; x.u[3] = d;
    return x.v;
}

__device__ __forceinline__ float bf16hi_to_f32(uint32_t hi) {
    return __builtin_bit_cast(float, hi);                 // hi already has low 16 = 0
}

// Per 16-edge tile (one wave):
//   hid GEMM: A=[e|1|0..] (16x32), B=W1ext (32x64) -> relu -> hid (16x64)
//   big GEMM: A=U[e][kn]=hid_k*h_n (16x1056), B=W2ext' (1056x16) -> m (16x16)
// hid round-trips LDS in EDGE-MAJOR parity-split layout so each lane reads all
// its 33 hid scalars with 4x ds_read_b128 + 1x ds_read_u16 up front.
__global__ __launch_bounds__(BLOCK, 5) void msg_mfma(
    const int*   __restrict__ idx,
    const float* __restrict__ h_w,
    const float* __restrict__ e_vw,
    const float* __restrict__ W1,   // [16][64]
    const float* __restrict__ b1,   // [64]
    const float* __restrict__ W2,   // [64][256]  ([k][m*16+n])
    const float* __restrict__ b2,   // [256]
    float*       __restrict__ out,  // [n_node][16], pre-zeroed
    int n_edge)
{
    // B-frag-ordered W2ext: sB[c*512 + q*128 + m*8 + j] = W2ext[2c+(q>>1)][m*16+(q&1)*8+j]
    __align__(16) __shared__ ushort sB[KCHUNKS * 512];    // 33792 B
    // B-frag-ordered W1ext: sW1[nt*512 + lane*8 + j] = W1ext[q*8+j][nt*16+col]
    __align__(16) __shared__ ushort sW1[4 * 512];         // 4096 B
    // per-wave hid, edge-major parity-split:
    //   sHid[w*1280 + p*640 + e*40 + c] = hid[e][k=2c+p]   (c = 0..32, 7 pad)
    __align__(16) __shared__ ushort sHid[WPB * 1280];     // 30720 B
    // total 68608 B -> 2 blocks/CU

    const int tid = threadIdx.x;

    // ---- stage W2ext fragments (once per block) ----
    for (int t = tid; t < KCHUNKS * 512; t += BLOCK) {
        int c = t >> 9, r = t & 511;
        int qq = r >> 7, m = (r >> 3) & 15, j = r & 7;
        int k = 2 * c + (qq >> 1);
        int n = ((qq & 1) << 3) + j;
        float v = 0.f;
        if (k < 64)       v = W2[k * 256 + m * 16 + n];
        else if (k == 64) v = b2[m * 16 + n];
        sB[t] = f32_to_bf16_rne(v);
    }
    // ---- stage W1ext fragments ----
    for (int t = tid; t < 4 * 512; t += BLOCK) {
        int j = t & 7, ln = (t >> 3) & 63, nt = t >> 9;
        int k = (ln >> 4) * 8 + j, n = nt * 16 + (ln & 15);
        float v = 0.f;
        if (k < 16)       v = W1[k * 64 + n];
        else if (k == 16) v = b1[n];
        sW1[t] = f32_to_bf16_rne(v);
    }

    const int lane = tid & 63;
    const int q    = lane >> 4;    // quad-row 0..3
    const int col  = lane & 15;
    const int w    = tid >> 6;

    // constant hid entries c=32: k=64 (p=0) -> 1.0 bias row, k=65 (p=1) -> 0
    sHid[w * 1280 + (q >> 1) * 640 + col * 40 + 32] =
        ((q >> 1) == 0) ? (ushort)0x3F80 : (ushort)0;
    __syncthreads();

    const int ntile = (n_edge + 15) >> 4;
    const int wave_id = blockIdx.x * WPB + w;
    const int wstride = gridDim.x * WPB;
    if (wave_id >= ntile) return;

    const int nhalf = (q & 1) << 3;
    const ushort* bRd   = &sB[q * 128 + col * 8];                         // + c*512
    const ushort* hidR  = &sHid[w * 1280 + (q >> 1) * 640 + col * 40];
    ushort*       hidWr = &sHid[w * 1280 + (col & 1) * 640 + (q * 4) * 40 + (col >> 1)];

    // ---- prefetch first tile (32-bit offsets: max offset < 2^27) ----
    int t = wave_id;
    float4 e0, e1, h0, h1; int vidx;
    {
        int row = min(t * 16 + col, n_edge - 1);
        const float4* ep = (const float4*)(e_vw + row * 16 + nhalf);
        e0 = ep[0]; e1 = ep[1];
        const float4* hp = (const float4*)(h_w + row * 16 + nhalf);
        h0 = hp[0]; h1 = hp[1];
        vidx = idx[row];
    }

    while (true) {
        // ---- issue next tile's loads before this tile's compute/atomics ----
        int tn = t + wstride;
        bool have_next = (tn < ntile);
        float4 ne0, ne1, nh0, nh1; int nvidx;
        if (have_next) {
            int row = min(tn * 16 + col, n_edge - 1);
            const float4* ep = (const float4*)(e_vw + row * 16 + nhalf);
            ne0 = ep[0]; ne1 = ep[1];
            const float4* hp = (const float4*)(h_w + row * 16 + nhalf);
            nh0 = hp[0]; nh1 = hp[1];
            nvidx = idx[row];
        }

        // ---- hid stage: 4 MFMAs, relu, trunc, edge-major LDS write ----
        uint32_t au0 = pack_trunc(e0.x, e0.y);
        uint32_t au1 = pack_trunc(e0.z, e0.w);
        uint32_t au2 = pack_trunc(e1.x, e1.y);
        uint32_t au3 = pack_trunc(e1.z, e1.w);
        if (q == 2)      { au0 = 0x00003F80u; au1 = au2 = au3 = 0; }  // bias row k=16
        else if (q == 3) { au0 = au1 = au2 = au3 = 0; }
        bf16x8 av = u4_as_bf16x8(au0, au1, au2, au3);

        #pragma unroll
        for (int nt = 0; nt < 4; nt++) {
            bf16x8 w1f = *(const bf16x8*)&sW1[nt * 512 + lane * 8];
            f32x4 hc = {0.f, 0.f, 0.f, 0.f};
            hc = __builtin_amdgcn_mfma_f32_16x16x32_bf16(av, w1f, hc, 0, 0, 0);
            // hc[i] = hid[e=q*4+i][k=nt*16+col]
            #pragma unroll
            for (int i = 0; i < 4; i++) {
                float r = fmaxf(hc[i], 0.f);
                hidWr[i * 40 + nt * 8] =
                    (ushort)(__builtin_bit_cast(uint32_t, r) >> 16);
            }
        }

        // ---- slurp this lane's 33 hid scalars into registers ----
        const uint4* hp4 = (const uint4*)hidR;
        uint4 ra = hp4[0], rb = hp4[1], rc = hp4[2], rd = hp4[3];
        uint32_t hkd[16] = {ra.x, ra.y, ra.z, ra.w, rb.x, rb.y, rb.z, rb.w,
                            rc.x, rc.y, rc.z, rc.w, rd.x, rd.y, rd.z, rd.w};
        uint32_t hlast = (uint32_t)hidR[32];

        // ---- big GEMM: 33 chunks ----
        float hf[8] = {h0.x, h0.y, h0.z, h0.w, h1.x, h1.y, h1.z, h1.w};
        f32x4 acc = {0.f, 0.f, 0.f, 0.f};
        #pragma unroll
        for (int c = 0; c < KCHUNKS; c++) {
            float hk;
            if (c == 32)      hk = bf16hi_to_f32(hlast << 16);
            else if (c & 1)   hk = bf16hi_to_f32(hkd[c >> 1] & 0xFFFF0000u);
            else              hk = bf16hi_to_f32(hkd[c >> 1] << 16);
            uint32_t a0 = pack_trunc(hk * hf[0], hk * hf[1]);
            uint32_t a1 = pack_trunc(hk * hf[2], hk * hf[3]);
            uint32_t a2 = pack_trunc(hk * hf[4], hk * hf[5]);
            uint32_t a3 = pack_trunc(hk * hf[6], hk * hf[7]);
            bf16x8 af  = u4_as_bf16x8(a0, a1, a2, a3);
            bf16x8 bfb = *(const bf16x8*)(bRd + c * 512);   // ds_read_b128
            acc = __builtin_amdgcn_mfma_f32_16x16x32_bf16(af, bfb, acc, 0, 0, 0);
        }

        // ---- epilogue: acc[i] = m[edge=q*4+i][m_out=col] -> atomics ----
        int nd0 = __shfl(vidx, q * 4 + 0);
        int nd1 = __shfl(vidx, q * 4 + 1);
        int nd2 = __shfl(vidx, q * 4 + 2);
        int nd3 = __shfl(vidx, q * 4 + 3);
        int r0 = t * 16 + q * 4;
        if (r0 + 0 < n_edge) atomicAdd(out + nd0 * 16 + col, acc[0]);
        if (r0 + 1 < n_edge) atomicAdd(out + nd1 * 16 + col, acc[1]);
        if (r0 + 2 < n_edge) atomicAdd(out + nd2 * 16 + col, acc[2]);
        if (r0 + 3 < n_edge) atomicAdd(out + nd3 * 16 + col, acc[3]);

        if (!have_next) break;
        t = tn;
        e0 = ne0; e1 = ne1; h0 = nh0; h1 = nh1; vidx = nvidx;
    }
}

extern "C" void kernel_launch(void* const* d_in, const int* in_sizes, int n_in,
                              void* d_out, int out_size, void* d_ws, size_t ws_size,
                              hipStream_t stream) {
    const int*   idx  = (const int*)  d_in[0];
    const float* h_w  = (const float*)d_in[1];
    const float* e_vw = (const float*)d_in[2];
    const float* W1   = (const float*)d_in[4];
    const float* b1   = (const float*)d_in[5];
    const float* W2   = (const float*)d_in[6];
    const float* b2   = (const float*)d_in[7];
    float* out = (float*)d_out;
    const int n_edge = in_sizes[0];

    hipMemsetAsync(out, 0, (size_t)out_size * sizeof(float), stream);
    msg_mfma<<<1024, BLOCK, 0, stream>>>(idx, h_w, e_vw, W1, b1, W2, b2, out, n_edge);
}

// Round 4
// 662.473 us; speedup vs baseline: 1.1045x; 1.1045x over previous
//
#include <hip/hip_runtime.h>
#include <stdint.h>

typedef __bf16 bf16x8 __attribute__((ext_vector_type(8)));
typedef float  f32x4  __attribute__((ext_vector_type(4)));

#define KCHUNKS 33              // K' = 66 rows (64 hid + bias + zero) x 16 n / 32
#define BLOCK   512             // 8 waves/block

// truncating f32->bf16 pack of two floats into one dword (x low, y high)
__device__ __forceinline__ uint32_t pack_trunc(float x, float y) {
    return __builtin_amdgcn_perm(__builtin_bit_cast(uint32_t, x),
                                 __builtin_bit_cast(uint32_t, y),
                                 0x03020706u);
}

__device__ __forceinline__ uint16_t f32_to_bf16_rne(float f) {
    uint32_t u = __builtin_bit_cast(uint32_t, f);
    u += 0x7FFFu + ((u >> 16) & 1u);
    return (uint16_t)(u >> 16);
}

__device__ __forceinline__ bf16x8 u4_as_bf16x8(uint32_t a, uint32_t b,
                                               uint32_t c, uint32_t d) {
    union { uint32_t u[4]; bf16x8 v; } x;
    x.u[0] = a; x.u[1] = b; x.u[2] = c; x.u[3] = d;
    return x.v;
}

// Per 16-edge tile (one wave):
//   hid GEMM (TRANSPOSED): D = W1ext^T * [e|1]^T -> hid^T[k][e] in C-layout
//     (operand swap: mfma(w1f, av); sW1 data serves as A-frag unchanged)
//   big GEMM: A = U[e][kn] = hid_k*h_n (16x1056), B = W2ext' (1056x16) -> m[e][16]
// hid values move lanes via ds_bpermute (no LDS storage, no bank conflicts):
//   lane (q,col) needs hid[2c+p][col]  (p = q>>1)
//   = parity half of packed dword hd[nt*2+a] in lane q_src*16+col,
//     nt = c>>3, q_src = (c>>1)&3, a = c&1  (all compile-time per chunk)
__global__ __launch_bounds__(BLOCK, 4) void msg_mfma(
    const int*   __restrict__ idx,
    const float* __restrict__ h_w,
    const float* __restrict__ e_vw,
    const float* __restrict__ W1,   // [16][64]
    const float* __restrict__ b1,   // [64]
    const float* __restrict__ W2,   // [64][256]  ([k][m*16+n])
    const float* __restrict__ b2,   // [256]
    float*       __restrict__ out,  // [n_node][16], pre-zeroed
    int n_edge)
{
    // B-frag-ordered W2ext: sB[c*512 + q*128 + m*8 + j] = W2ext[2c+(q>>1)][m*16+(q&1)*8+j]
    __align__(16) __shared__ ushort sB[KCHUNKS * 512];    // 33792 B
    // frag-ordered W1ext: sW1[nt*512 + lane*8 + j] = W1ext[ee=q*8+j][nt*16+col]
    __align__(16) __shared__ ushort sW1[4 * 512];         // 4096 B
    // total 37888 B

    const int tid = threadIdx.x;

    // ---- stage W2ext fragments (once per block) ----
    for (int t = tid; t < KCHUNKS * 512; t += BLOCK) {
        int c = t >> 9, r = t & 511;
        int qq = r >> 7, m = (r >> 3) & 15, j = r & 7;
        int k = 2 * c + (qq >> 1);
        int n = ((qq & 1) << 3) + j;
        float v = 0.f;
        if (k < 64)       v = W2[k * 256 + m * 16 + n];
        else if (k == 64) v = b2[m * 16 + n];
        sB[t] = f32_to_bf16_rne(v);
    }
    // ---- stage W1ext fragments ----
    for (int t = tid; t < 4 * 512; t += BLOCK) {
        int j = t & 7, ln = (t >> 3) & 63, nt = t >> 9;
        int k = (ln >> 4) * 8 + j, n = nt * 16 + (ln & 15);
        float v = 0.f;
        if (k < 16)       v = W1[k * 64 + n];
        else if (k == 16) v = b1[n];
        sW1[t] = f32_to_bf16_rne(v);
    }
    __syncthreads();

    const int lane = tid & 63;
    const int q    = lane >> 4;    // quad-row 0..3
    const int col  = lane & 15;
    const int w    = tid >> 6;
    const int p    = q >> 1;       // k-parity this lane consumes in big GEMM

    // W1ext fragments persistent in registers (reused every tile)
    bf16x8 w1f[4];
    #pragma unroll
    for (int nt = 0; nt < 4; nt++)
        w1f[nt] = *(const bf16x8*)&sW1[nt * 512 + lane * 8];

    // bpermute byte addresses for source lanes q_src*16 + col
    const int va0 = col * 4, va1 = va0 + 64, va2 = va0 + 128, va3 = va0 + 192;
    const uint32_t shp = (uint32_t)((p ^ 1) * 16);  // parity extract shift
    const float hk_bias = (p == 0) ? 1.0f : 0.0f;   // chunk 32: k=64 ->1.0, k=65 ->0

    const int nhalf = (q & 1) << 3;
    const ushort* bRd = &sB[q * 128 + col * 8];     // + c*512

    const int ntile = (n_edge + 15) >> 4;
    const int wave_id = blockIdx.x * (BLOCK / 64) + w;
    const int wstride = gridDim.x * (BLOCK / 64);
    if (wave_id >= ntile) return;

    // ---- prefetch first tile ----
    int t = wave_id;
    float4 e0, e1, h0, h1; int vidx;
    {
        int row = min(t * 16 + col, n_edge - 1);
        const float4* ep = (const float4*)(e_vw + (size_t)row * 16 + nhalf);
        e0 = ep[0]; e1 = ep[1];
        const float4* hp = (const float4*)(h_w + (size_t)row * 16 + nhalf);
        h0 = hp[0]; h1 = hp[1];
        vidx = idx[row];
    }

    while (true) {
        // ---- issue next tile's loads before this tile's compute/atomics ----
        int tn = t + wstride;
        bool have_next = (tn < ntile);
        float4 ne0, ne1, nh0, nh1; int nvidx;
        if (have_next) {
            int row = min(tn * 16 + col, n_edge - 1);
            const float4* ep = (const float4*)(e_vw + (size_t)row * 16 + nhalf);
            ne0 = ep[0]; ne1 = ep[1];
            const float4* hp = (const float4*)(h_w + (size_t)row * 16 + nhalf);
            nh0 = hp[0]; nh1 = hp[1];
            nvidx = idx[row];
        }

        // ---- edge B-frag: B[ee][e=col], ee = q*8+j; row 16 = bias 1.0 ----
        uint32_t au0 = pack_trunc(e0.x, e0.y);
        uint32_t au1 = pack_trunc(e0.z, e0.w);
        uint32_t au2 = pack_trunc(e1.x, e1.y);
        uint32_t au3 = pack_trunc(e1.z, e1.w);
        if (q == 2)      { au0 = 0x00003F80u; au1 = au2 = au3 = 0; }
        else if (q == 3) { au0 = au1 = au2 = au3 = 0; }
        bf16x8 av = u4_as_bf16x8(au0, au1, au2, au3);

        // ---- transposed hid GEMM: D[k_out][e], k_out = nt*16 + q*4 + i ----
        f32x4 hc[4];
        #pragma unroll
        for (int nt = 0; nt < 4; nt++) {
            f32x4 z = {0.f, 0.f, 0.f, 0.f};
            hc[nt] = __builtin_amdgcn_mfma_f32_16x16x32_bf16(w1f[nt], av, z, 0, 0, 0);
        }
        // relu + pack parity pairs: hd[nt*2+a] = (bf16(k even), bf16(k odd))
        uint32_t hd[8];
        #pragma unroll
        for (int nt = 0; nt < 4; nt++) {
            hd[nt * 2 + 0] = pack_trunc(fmaxf(hc[nt][0], 0.f), fmaxf(hc[nt][1], 0.f));
            hd[nt * 2 + 1] = pack_trunc(fmaxf(hc[nt][2], 0.f), fmaxf(hc[nt][3], 0.f));
        }

        // ---- big GEMM: 33 chunks over kn ----
        float hf[8] = {h0.x, h0.y, h0.z, h0.w, h1.x, h1.y, h1.z, h1.w};
        f32x4 acc = {0.f, 0.f, 0.f, 0.f};
        #pragma unroll
        for (int c = 0; c < KCHUNKS; c++) {
            float hk;
            if (c == 32) {
                hk = hk_bias;
            } else {
                const int a = c & 1, qs = (c >> 1) & 3, nt = c >> 3;
                const int vaddr = (qs == 0) ? va0 : (qs == 1) ? va1
                                : (qs == 2) ? va2 : va3;
                uint32_t dgot = (uint32_t)__builtin_amdgcn_ds_bpermute(
                    vaddr, (int)hd[nt * 2 + a]);
                hk = __builtin_bit_cast(float, (dgot << shp) & 0xFFFF0000u);
            }
            uint32_t a0 = pack_trunc(hk * hf[0], hk * hf[1]);
            uint32_t a1 = pack_trunc(hk * hf[2], hk * hf[3]);
            uint32_t a2 = pack_trunc(hk * hf[4], hk * hf[5]);
            uint32_t a3 = pack_trunc(hk * hf[6], hk * hf[7]);
            bf16x8 af  = u4_as_bf16x8(a0, a1, a2, a3);
            bf16x8 bfb = *(const bf16x8*)(bRd + c * 512);   // ds_read_b128
            acc = __builtin_amdgcn_mfma_f32_16x16x32_bf16(af, bfb, acc, 0, 0, 0);
        }

        // ---- epilogue: acc[i] = m[edge=q*4+i][m_out=col] -> atomics ----
        int nd0 = __shfl(vidx, q * 4 + 0);
        int nd1 = __shfl(vidx, q * 4 + 1);
        int nd2 = __shfl(vidx, q * 4 + 2);
        int nd3 = __shfl(vidx, q * 4 + 3);
        int r0 = t * 16 + q * 4;
        if (r0 + 0 < n_edge) atomicAdd(out + (size_t)nd0 * 16 + col, acc[0]);
        if (r0 + 1 < n_edge) atomicAdd(out + (size_t)nd1 * 16 + col, acc[1]);
        if (r0 + 2 < n_edge) atomicAdd(out + (size_t)nd2 * 16 + col, acc[2]);
        if (r0 + 3 < n_edge) atomicAdd(out + (size_t)nd3 * 16 + col, acc[3]);

        if (!have_next) break;
        t = tn;
        e0 = ne0; e1 = ne1; h0 = nh0; h1 = nh1; vidx = nvidx;
    }
}

extern "C" void kernel_launch(void* const* d_in, const int* in_sizes, int n_in,
                              void* d_out, int out_size, void* d_ws, size_t ws_size,
                              hipStream_t stream) {
    const int*   idx  = (const int*)  d_in[0];
    const float* h_w  = (const float*)d_in[1];
    const float* e_vw = (const float*)d_in[2];
    const float* W1   = (const float*)d_in[4];
    const float* b1   = (const float*)d_in[5];
    const float* W2   = (const float*)d_in[6];
    const float* b2   = (const float*)d_in[7];
    float* out = (float*)d_out;
    const int n_edge = in_sizes[0];

    hipMemsetAsync(out, 0, (size_t)out_size * sizeof(float), stream);
    msg_mfma<<<1600, BLOCK, 0, stream>>>(idx, h_w, e_vw, W1, b1, W2, b2, out, n_edge);
}

// Round 5
// 563.073 us; speedup vs baseline: 1.2994x; 1.1765x over previous
//
#include <hip/hip_runtime.h>
#include <stdint.h>

typedef __bf16 bf16x8 __attribute__((ext_vector_type(8)));
typedef float  f32x4  __attribute__((ext_vector_type(4)));

#define KCHUNKS 33              // K' = 66 rows (64 hid + bias + zero) x 16 n / 32
#define BLOCK   256             // 4 waves/block; __launch_bounds__(256,3) is the
                                // ONLY observed spill-free config (VGPR cap ~170).
                                // (768,5)->48 VGPR and (512,4)->64 VGPR both spilled
                                // to scratch (+0.8-1.1 GB HBM FETCH). Do not raise.

// truncating f32->bf16 pack of two floats into one dword (x low, y high)
__device__ __forceinline__ uint32_t pack_trunc(float x, float y) {
    return __builtin_amdgcn_perm(__builtin_bit_cast(uint32_t, x),
                                 __builtin_bit_cast(uint32_t, y),
                                 0x03020706u);
}

__device__ __forceinline__ uint16_t f32_to_bf16_rne(float f) {
    uint32_t u = __builtin_bit_cast(uint32_t, f);
    u += 0x7FFFu + ((u >> 16) & 1u);
    return (uint16_t)(u >> 16);
}

__device__ __forceinline__ bf16x8 u4_as_bf16x8(uint32_t a, uint32_t b,
                                               uint32_t c, uint32_t d) {
    union { uint32_t u[4]; bf16x8 v; } x;
    x.u[0] = a; x.u[1] = b; x.u[2] = c; x.u[3] = d;
    return x.v;
}

// Per iteration a wave handles TWO 16-edge tiles (A,B) so each W2' B-fragment
// ds_read_b128 feeds two MFMAs (LDS pipe was the modeled bottleneck).
//   hid GEMM (transposed): D = W1ext^T x [e|1]^T -> hid^T[k][e] in C-layout
//   big GEMM: U[e][kn] = hid_k*h_n (16x1056) x W2ext' (1056x16) -> m[e][16]
// hid moves lanes via ds_bpermute (zero bank conflicts, no LDS storage):
//   lane (q,col) chunk c needs hid[2c+p][col], p=q>>1, sitting in lane
//   qs*16+col dword hd[nt*2+a], qs=(c>>1)&3, nt=c>>3, a=c&1.
__global__ __launch_bounds__(BLOCK, 3) void msg_mfma(
    const int*   __restrict__ idx,
    const float* __restrict__ h_w,
    const float* __restrict__ e_vw,
    const float* __restrict__ W1,   // [16][64]
    const float* __restrict__ b1,   // [64]
    const float* __restrict__ W2,   // [64][256]  ([k][m*16+n])
    const float* __restrict__ b2,   // [256]
    float*       __restrict__ out,  // [n_node][16], pre-zeroed
    int n_edge)
{
    // B-frag-ordered W2ext: sB[c*512 + q*128 + m*8 + j] = W2ext[2c+(q>>1)][m*16+(q&1)*8+j]
    __align__(16) __shared__ ushort sB[KCHUNKS * 512];    // 33792 B
    // frag-ordered W1ext: sW1[nt*512 + lane*8 + j] = W1ext[k=q*8+j][nt*16+col]
    __align__(16) __shared__ ushort sW1[4 * 512];         // 4096 B

    const int tid = threadIdx.x;

    for (int t = tid; t < KCHUNKS * 512; t += BLOCK) {
        int c = t >> 9, r = t & 511;
        int qq = r >> 7, m = (r >> 3) & 15, j = r & 7;
        int k = 2 * c + (qq >> 1);
        int n = ((qq & 1) << 3) + j;
        float v = 0.f;
        if (k < 64)       v = W2[k * 256 + m * 16 + n];
        else if (k == 64) v = b2[m * 16 + n];
        sB[t] = f32_to_bf16_rne(v);
    }
    for (int t = tid; t < 4 * 512; t += BLOCK) {
        int j = t & 7, ln = (t >> 3) & 63, nt = t >> 9;
        int k = (ln >> 4) * 8 + j, n = nt * 16 + (ln & 15);
        float v = 0.f;
        if (k < 16)       v = W1[k * 64 + n];
        else if (k == 16) v = b1[n];
        sW1[t] = f32_to_bf16_rne(v);
    }
    __syncthreads();

    const int lane = tid & 63;
    const int q    = lane >> 4;
    const int col  = lane & 15;
    const int w    = tid >> 6;
    const int p    = q >> 1;

    bf16x8 w1f[4];
    #pragma unroll
    for (int nt = 0; nt < 4; nt++)
        w1f[nt] = *(const bf16x8*)&sW1[nt * 512 + lane * 8];

    const int va0 = col * 4, va1 = va0 + 64, va2 = va0 + 128, va3 = va0 + 192;
    const uint32_t shp = (uint32_t)((p ^ 1) * 16);
    const float hk_bias = (p == 0) ? 1.0f : 0.0f;

    const int nhalf = (q & 1) << 3;
    const ushort* bRd = &sB[q * 128 + col * 8];

    const int ntile = (n_edge + 15) >> 4;
    const int npair = (ntile + 1) >> 1;
    int pair = blockIdx.x * 4 + w;
    const int pstride = gridDim.x * 4;
    if (pair >= npair) return;

    // ---- prefetch first pair ----
    float4 eA0, eA1, hA0, hA1, eB0, eB1, hB0, hB1; int idxA, idxB;
    {
        int tA = pair * 2;
        int rowA = min(tA * 16 + col, n_edge - 1);
        int rowB = min(tA * 16 + 16 + col, n_edge - 1);
        const float4* ep = (const float4*)(e_vw + (size_t)rowA * 16 + nhalf);
        eA0 = ep[0]; eA1 = ep[1];
        const float4* hp = (const float4*)(h_w + (size_t)rowA * 16 + nhalf);
        hA0 = hp[0]; hA1 = hp[1];
        const float4* eq = (const float4*)(e_vw + (size_t)rowB * 16 + nhalf);
        eB0 = eq[0]; eB1 = eq[1];
        const float4* hq = (const float4*)(h_w + (size_t)rowB * 16 + nhalf);
        hB0 = hq[0]; hB1 = hq[1];
        idxA = idx[rowA]; idxB = idx[rowB];
    }

    while (true) {
        int pn = pair + pstride;
        bool have_next = (pn < npair);
        float4 neA0, neA1, nhA0, nhA1, neB0, neB1, nhB0, nhB1; int nidxA, nidxB;
        if (have_next) {
            int tA = pn * 2;
            int rowA = min(tA * 16 + col, n_edge - 1);
            int rowB = min(tA * 16 + 16 + col, n_edge - 1);
            const float4* ep = (const float4*)(e_vw + (size_t)rowA * 16 + nhalf);
            neA0 = ep[0]; neA1 = ep[1];
            const float4* hp = (const float4*)(h_w + (size_t)rowA * 16 + nhalf);
            nhA0 = hp[0]; nhA1 = hp[1];
            const float4* eq = (const float4*)(e_vw + (size_t)rowB * 16 + nhalf);
            neB0 = eq[0]; neB1 = eq[1];
            const float4* hq = (const float4*)(h_w + (size_t)rowB * 16 + nhalf);
            nhB0 = hq[0]; nhB1 = hq[1];
            nidxA = idx[rowA]; nidxB = idx[rowB];
        }

        // ---- hid GEMMs for both tiles ----
        uint32_t hdA[8], hdB[8];
        {
            uint32_t a0 = pack_trunc(eA0.x, eA0.y), a1 = pack_trunc(eA0.z, eA0.w);
            uint32_t a2 = pack_trunc(eA1.x, eA1.y), a3 = pack_trunc(eA1.z, eA1.w);
            if (q == 2)      { a0 = 0x00003F80u; a1 = a2 = a3 = 0; }
            else if (q == 3) { a0 = a1 = a2 = a3 = 0; }
            bf16x8 av = u4_as_bf16x8(a0, a1, a2, a3);
            #pragma unroll
            for (int nt = 0; nt < 4; nt++) {
                f32x4 z = {0.f, 0.f, 0.f, 0.f};
                f32x4 hc = __builtin_amdgcn_mfma_f32_16x16x32_bf16(w1f[nt], av, z, 0, 0, 0);
                hdA[nt*2+0] = pack_trunc(fmaxf(hc[0], 0.f), fmaxf(hc[1], 0.f));
                hdA[nt*2+1] = pack_trunc(fmaxf(hc[2], 0.f), fmaxf(hc[3], 0.f));
            }
        }
        {
            uint32_t a0 = pack_trunc(eB0.x, eB0.y), a1 = pack_trunc(eB0.z, eB0.w);
            uint32_t a2 = pack_trunc(eB1.x, eB1.y), a3 = pack_trunc(eB1.z, eB1.w);
            if (q == 2)      { a0 = 0x00003F80u; a1 = a2 = a3 = 0; }
            else if (q == 3) { a0 = a1 = a2 = a3 = 0; }
            bf16x8 av = u4_as_bf16x8(a0, a1, a2, a3);
            #pragma unroll
            for (int nt = 0; nt < 4; nt++) {
                f32x4 z = {0.f, 0.f, 0.f, 0.f};
                f32x4 hc = __builtin_amdgcn_mfma_f32_16x16x32_bf16(w1f[nt], av, z, 0, 0, 0);
                hdB[nt*2+0] = pack_trunc(fmaxf(hc[0], 0.f), fmaxf(hc[1], 0.f));
                hdB[nt*2+1] = pack_trunc(fmaxf(hc[2], 0.f), fmaxf(hc[3], 0.f));
            }
        }

        // ---- big GEMM: 33 chunks, one B-frag read feeds both tiles ----
        float hfA[8] = {hA0.x, hA0.y, hA0.z, hA0.w, hA1.x, hA1.y, hA1.z, hA1.w};
        float hfB[8] = {hB0.x, hB0.y, hB0.z, hB0.w, hB1.x, hB1.y, hB1.z, hB1.w};
        f32x4 accA = {0.f, 0.f, 0.f, 0.f};
        f32x4 accB = {0.f, 0.f, 0.f, 0.f};
        #pragma unroll
        for (int c = 0; c < KCHUNKS; c++) {
            float hkA, hkB;
            if (c == 32) {
                hkA = hk_bias; hkB = hk_bias;
            } else {
                const int a = c & 1, qs = (c >> 1) & 3, nt = c >> 3;
                const int vaddr = (qs == 0) ? va0 : (qs == 1) ? va1
                                : (qs == 2) ? va2 : va3;
                uint32_t gA = (uint32_t)__builtin_amdgcn_ds_bpermute(vaddr, (int)hdA[nt*2+a]);
                uint32_t gB = (uint32_t)__builtin_amdgcn_ds_bpermute(vaddr, (int)hdB[nt*2+a]);
                hkA = __builtin_bit_cast(float, (gA << shp) & 0xFFFF0000u);
                hkB = __builtin_bit_cast(float, (gB << shp) & 0xFFFF0000u);
            }
            bf16x8 bfb = *(const bf16x8*)(bRd + c * 512);   // ds_read_b128 (shared)
            uint32_t a0 = pack_trunc(hkA * hfA[0], hkA * hfA[1]);
            uint32_t a1 = pack_trunc(hkA * hfA[2], hkA * hfA[3]);
            uint32_t a2 = pack_trunc(hkA * hfA[4], hkA * hfA[5]);
            uint32_t a3 = pack_trunc(hkA * hfA[6], hkA * hfA[7]);
            accA = __builtin_amdgcn_mfma_f32_16x16x32_bf16(
                       u4_as_bf16x8(a0, a1, a2, a3), bfb, accA, 0, 0, 0);
            uint32_t b0 = pack_trunc(hkB * hfB[0], hkB * hfB[1]);
            uint32_t b1_ = pack_trunc(hkB * hfB[2], hkB * hfB[3]);
            uint32_t b2_ = pack_trunc(hkB * hfB[4], hkB * hfB[5]);
            uint32_t b3 = pack_trunc(hkB * hfB[6], hkB * hfB[7]);
            accB = __builtin_amdgcn_mfma_f32_16x16x32_bf16(
                       u4_as_bf16x8(b0, b1_, b2_, b3), bfb, accB, 0, 0, 0);
        }

        // ---- epilogue: atomics for both tiles ----
        {
            int r0 = pair * 32 + q * 4;
            int nd0 = __shfl(idxA, q * 4 + 0);
            int nd1 = __shfl(idxA, q * 4 + 1);
            int nd2 = __shfl(idxA, q * 4 + 2);
            int nd3 = __shfl(idxA, q * 4 + 3);
            if (r0 + 0 < n_edge) atomicAdd(out + (size_t)nd0 * 16 + col, accA[0]);
            if (r0 + 1 < n_edge) atomicAdd(out + (size_t)nd1 * 16 + col, accA[1]);
            if (r0 + 2 < n_edge) atomicAdd(out + (size_t)nd2 * 16 + col, accA[2]);
            if (r0 + 3 < n_edge) atomicAdd(out + (size_t)nd3 * 16 + col, accA[3]);
            int r1 = r0 + 16;
            int md0 = __shfl(idxB, q * 4 + 0);
            int md1 = __shfl(idxB, q * 4 + 1);
            int md2 = __shfl(idxB, q * 4 + 2);
            int md3 = __shfl(idxB, q * 4 + 3);
            if (r1 + 0 < n_edge) atomicAdd(out + (size_t)md0 * 16 + col, accB[0]);
            if (r1 + 1 < n_edge) atomicAdd(out + (size_t)md1 * 16 + col, accB[1]);
            if (r1 + 2 < n_edge) atomicAdd(out + (size_t)md2 * 16 + col, accB[2]);
            if (r1 + 3 < n_edge) atomicAdd(out + (size_t)md3 * 16 + col, accB[3]);
        }

        if (!have_next) break;
        pair = pn;
        eA0 = neA0; eA1 = neA1; hA0 = nhA0; hA1 = nhA1;
        eB0 = neB0; eB1 = neB1; hB0 = nhB0; hB1 = nhB1;
        idxA = nidxA; idxB = nidxB;
    }
}

extern "C" void kernel_launch(void* const* d_in, const int* in_sizes, int n_in,
                              void* d_out, int out_size, void* d_ws, size_t ws_size,
                              hipStream_t stream) {
    const int*   idx  = (const int*)  d_in[0];
    const float* h_w  = (const float*)d_in[1];
    const float* e_vw = (const float*)d_in[2];
    const float* W1   = (const float*)d_in[4];
    const float* b1   = (const float*)d_in[5];
    const float* W2   = (const float*)d_in[6];
    const float* b2   = (const float*)d_in[7];
    float* out = (float*)d_out;
    const int n_edge = in_sizes[0];

    hipMemsetAsync(out, 0, (size_t)out_size * sizeof(float), stream);
    msg_mfma<<<768, BLOCK, 0, stream>>>(idx, h_w, e_vw, W1, b1, W2, b2, out, n_edge);
}